// Round 13
// baseline (335.270 us; speedup 1.0000x reference)
//
#include <hip/hip_runtime.h>
#include <hip/hip_bf16.h>
#include <hip/hip_cooperative_groups.h>
#include <math.h>

namespace cg = cooperative_groups;

// N=10000, E=320000, in_dim=256, heads=4, hidden=64 (C1=256), out=40
#define IN_DIM 256
#define C1 256
#define H1 4
#define OUT_DIM 40
#define W2PAD 48
#define NEG_SLOPE 0.2f
#define DSTRIDE 128  // padded CSR stride; max degree ~58 << 128

typedef __attribute__((ext_vector_type(8))) short bf16x8;
typedef __attribute__((ext_vector_type(4))) float f32x4;
typedef __attribute__((ext_vector_type(2))) float f32x2;

#define XS_LD 264  // LDS row stride (u16): 256 + 8 pad
#define SHBYTES (64 * XS_LD * 2)  // 33792 B shared arena

__device__ __forceinline__ unsigned short f2bf(float f) {
    union { float f; unsigned u; } c; c.f = f;
    unsigned r = c.u + 0x7fffu + ((c.u >> 16) & 1u);
    return (unsigned short)(r >> 16);
}

__device__ __forceinline__ unsigned char f2fp8(float f) {
    return (unsigned char)__builtin_amdgcn_cvt_pk_fp8_f32(f, 0.f, 0, false);
}

__device__ __forceinline__ float sel4(float4 v, int h) {
    float r = v.x;
    r = (h == 1) ? v.y : r;
    r = (h == 2) ? v.z : r;
    r = (h == 3) ? v.w : r;
    return r;
}

__device__ __forceinline__ float leaky(float v) {
    return (v >= 0.0f) ? v : NEG_SLOPE * v;
}

struct MegaArgs {
    const float* x; const int* ei;
    const float* W1; const float* a_src1; const float* a_dst1; const float* bias1;
    const float* W2; const float* a_src2; const float* a_dst2; const float* bias2;
    float* out;
    unsigned char* h1;
    unsigned short* W1t; unsigned short* W2t; unsigned short* agg1b; unsigned short* h2b;
    float* as1; float* ad1; float* as2; float* ad2; float* w2s; float* w2d;
    int* fill; unsigned short* srcs;
    int N, E, ET, G1, GS;
};

// ---------------- phase bodies (verbatim r10 logic, block-index virtualized) ----------------

__device__ void prep_w1t_tile(char* shbuf, int vb, const float* __restrict__ W1,
                              unsigned short* __restrict__ W1t, int t) {
    float (*s32)[33] = (float (*)[33])shbuf;
    __syncthreads();
    int r0 = (vb >> 3) * 32;   // k
    int c0 = (vb & 7) * 32;    // col
    for (int i = t; i < 1024; i += 256) {
        int lr = i >> 5, lc = i & 31;
        s32[lr][lc] = W1[(r0 + lr) * 256 + c0 + lc];
    }
    __syncthreads();
    for (int i = t; i < 1024; i += 256) {
        int oc = i >> 5, ok = i & 31;
        W1t[(c0 + oc) * 256 + r0 + ok] = f2bf(s32[ok][oc]);
    }
}

__device__ void gemm1_tile(char* shbuf, int vb, const MegaArgs& a, int t) {
    unsigned short* xs = (unsigned short*)shbuf;
    int n0 = vb * 64;
    __syncthreads();  // protect shared arena from previous iteration
    for (int i = t; i < 4096; i += 256) {
        int r = i >> 6, c4 = i & 63;
        int n = n0 + r;
        float4 v = (n < a.N) ? ((const float4*)a.x)[(size_t)n * 64 + c4]
                             : make_float4(0.f, 0.f, 0.f, 0.f);
        uint2 pk;
        pk.x = (unsigned)f2bf(v.x) | ((unsigned)f2bf(v.y) << 16);
        pk.y = (unsigned)f2bf(v.z) | ((unsigned)f2bf(v.w) << 16);
        *((uint2*)&xs[r * XS_LD + c4 * 4]) = pk;
    }
    __syncthreads();

    int wv = t >> 6, lane = t & 63;
    int quad = lane >> 4, ln = lane & 15;

    f32x4 acc[4][4];
#pragma unroll
    for (int mt = 0; mt < 4; ++mt)
#pragma unroll
        for (int nt = 0; nt < 4; ++nt) acc[mt][nt] = (f32x4){0.f, 0.f, 0.f, 0.f};

#pragma unroll
    for (int kb = 0; kb < 8; ++kb) {
        bf16x8 af[4], bf[4];
#pragma unroll
        for (int mt = 0; mt < 4; ++mt)
            af[mt] = *((bf16x8*)&xs[(mt * 16 + ln) * XS_LD + kb * 32 + quad * 8]);
#pragma unroll
        for (int nt = 0; nt < 4; ++nt)
            bf[nt] = *((const bf16x8*)(a.W1t + ((wv * 64 + nt * 16 + ln) * 256 + kb * 32 + quad * 8)));
#pragma unroll
        for (int mt = 0; mt < 4; ++mt)
#pragma unroll
            for (int nt = 0; nt < 4; ++nt)
                acc[mt][nt] = __builtin_amdgcn_mfma_f32_16x16x32_bf16(af[mt], bf[nt], acc[mt][nt], 0, 0, 0);
    }

    float asv[4], adv[4];
#pragma unroll
    for (int nt = 0; nt < 4; ++nt) {
        int col = wv * 64 + nt * 16 + ln;
        asv[nt] = a.a_src1[col];
        adv[nt] = a.a_dst1[col];
    }
#pragma unroll
    for (int mt = 0; mt < 4; ++mt) {
        float ds[4] = {0.f, 0.f, 0.f, 0.f};
        float dd[4] = {0.f, 0.f, 0.f, 0.f};
#pragma unroll
        for (int nt = 0; nt < 4; ++nt) {
#pragma unroll
            for (int r = 0; r < 4; ++r) {
                float v = acc[mt][nt][r];
                ds[r] += v * asv[nt];
                dd[r] += v * adv[nt];
            }
        }
#pragma unroll
        for (int r = 0; r < 4; ++r) {
            float vs = ds[r], vd = dd[r];
#pragma unroll
            for (int o = 1; o < 16; o <<= 1) {
                vs += __shfl_xor(vs, o);
                vd += __shfl_xor(vd, o);
            }
            if (ln == 0) {
                int node = n0 + mt * 16 + quad * 4 + r;
                if (node < a.N) {
                    a.as1[node * H1 + wv] = vs;
                    a.ad1[node * H1 + wv] = vd;
                }
            }
        }
    }

    // h1 store: repack fp8 tile through LDS -> coalesced dwordx4 row stores
    __syncthreads();
    unsigned char* bt = (unsigned char*)xs;  // 64 x 256 byte tile
#pragma unroll
    for (int mt = 0; mt < 4; ++mt)
#pragma unroll
        for (int nt = 0; nt < 4; ++nt)
#pragma unroll
            for (int r = 0; r < 4; ++r)
                bt[(mt * 16 + quad * 4 + r) * 256 + wv * 64 + nt * 16 + ln] = f2fp8(acc[mt][nt][r]);
    __syncthreads();
    const uint4* bt4 = (const uint4*)bt;
    uint4* h14 = (uint4*)(a.h1 + (size_t)n0 * C1);
    for (int i = t; i < 1024; i += 256) {
        int row = i >> 4;
        if (n0 + row < a.N) h14[i] = bt4[i];
    }
}

__device__ void scatter_chunk(int vb, const MegaArgs& a, int t) {
    int eb = vb * 2048 + t;
#pragma unroll
    for (int k = 0; k < 8; ++k) {
        int e = eb + k * 256;
        if (e < a.ET) {
            int s, d;
            if (e < a.E) { s = a.ei[e]; d = a.ei[a.E + e]; }
            else         { s = e - a.E; d = s; }
            int pos = atomicAdd(&a.fill[d << 4], 1);
            a.srcs[(d << 7) + pos] = (unsigned short)s;
        }
    }
}

__device__ void node1_vb(char* shbuf, int vb, const MegaArgs& a, int tid) {
    int w = tid >> 6, lane = tid & 63;
    int n = vb * 4 + w;
    float4 (*es)[64] = (float4 (*)[64])shbuf;
    if (n < a.N) {
        int start = n << 7;
        int end = start + a.fill[n << 4];
        const float4* as4 = (const float4*)a.as1;
        float4 adn = ((const float4*)a.ad1)[n];
        int h = lane >> 4;
        const float* esw = (const float*)&es[w][0];

        float4 S4 = make_float4(0.f, 0.f, 0.f, 0.f);
        float ac0 = 0.f, ac1 = 0.f, ac2 = 0.f, ac3 = 0.f;

        for (int c = start; c < end; c += 64) {
            int cnt = min(64, end - c);
            int idx = c + lane;
            int sreg = (idx < end) ? (int)a.srcs[idx] : 0;
            float4 ex = make_float4(0.f, 0.f, 0.f, 0.f);
            if (idx < end) {
                float4 av = as4[sreg];
                ex.x = __expf(leaky(av.x + adn.x));
                ex.y = __expf(leaky(av.y + adn.y));
                ex.z = __expf(leaky(av.z + adn.z));
                ex.w = __expf(leaky(av.w + adn.w));
            }
            S4.x += ex.x; S4.y += ex.y; S4.z += ex.z; S4.w += ex.w;
            es[w][lane] = ex;

            int i = 0;
            for (; i + 7 < cnt; i += 8) {
                int s[8]; float al[8]; unsigned r[8];
#pragma unroll
                for (int k = 0; k < 8; ++k) {
                    s[k] = __shfl(sreg, i + k);
                    al[k] = esw[(i + k) * 4 + h];
                }
#pragma unroll
                for (int k = 0; k < 8; ++k)
                    r[k] = ((const unsigned*)(a.h1 + (size_t)s[k] * C1))[lane];
#pragma unroll
                for (int k = 0; k < 8; ++k) {
                    f32x2 lo = __builtin_amdgcn_cvt_pk_f32_fp8(r[k], false);
                    f32x2 hi = __builtin_amdgcn_cvt_pk_f32_fp8(r[k], true);
                    ac0 += al[k] * lo.x;
                    ac1 += al[k] * lo.y;
                    ac2 += al[k] * hi.x;
                    ac3 += al[k] * hi.y;
                }
            }
            for (; i < cnt; ++i) {
                int s0 = __shfl(sreg, i);
                float a0 = esw[i * 4 + h];
                unsigned r0 = ((const unsigned*)(a.h1 + (size_t)s0 * C1))[lane];
                f32x2 lo = __builtin_amdgcn_cvt_pk_f32_fp8(r0, false);
                f32x2 hi = __builtin_amdgcn_cvt_pk_f32_fp8(r0, true);
                ac0 += a0 * lo.x;
                ac1 += a0 * lo.y;
                ac2 += a0 * hi.x;
                ac3 += a0 * hi.y;
            }
        }

#pragma unroll
        for (int o = 32; o > 0; o >>= 1) {
            S4.x += __shfl_xor(S4.x, o);
            S4.y += __shfl_xor(S4.y, o);
            S4.z += __shfl_xor(S4.z, o);
            S4.w += __shfl_xor(S4.w, o);
        }
        float iS = 1.0f / sel4(S4, h);
        float4 b = ((const float4*)a.bias1)[lane];
        float v0 = fmaxf(ac0 * iS + b.x, 0.f);
        float v1 = fmaxf(ac1 * iS + b.y, 0.f);
        float v2 = fmaxf(ac2 * iS + b.z, 0.f);
        float v3 = fmaxf(ac3 * iS + b.w, 0.f);
        uint2 pk;
        pk.x = (unsigned)f2bf(v0) | ((unsigned)f2bf(v1) << 16);
        pk.y = (unsigned)f2bf(v2) | ((unsigned)f2bf(v3) << 16);
        ((uint2*)(a.agg1b + (size_t)n * C1))[lane] = pk;

        float4 ws = ((const float4*)a.w2s)[lane];
        float4 wd = ((const float4*)a.w2d)[lane];
        float ps = v0 * ws.x + v1 * ws.y + v2 * ws.z + v3 * ws.w;
        float pd = v0 * wd.x + v1 * wd.y + v2 * wd.z + v3 * wd.w;
#pragma unroll
        for (int o = 32; o > 0; o >>= 1) {
            ps += __shfl_xor(ps, o);
            pd += __shfl_xor(pd, o);
        }
        if (lane == 0) { a.as2[n] = ps; a.ad2[n] = pd; }
    }
}

__device__ void gemm2m_vb(int vb, const MegaArgs& a, int t) {
    int wv = t >> 6, lane = t & 63;
    int quad = lane >> 4, ln = lane & 15;
    int n0 = vb * 64;
    int mrow = n0 + wv * 16 + ln;

    f32x4 acc[3];
#pragma unroll
    for (int nt = 0; nt < 3; ++nt) acc[nt] = (f32x4){0.f, 0.f, 0.f, 0.f};

#pragma unroll
    for (int kb = 0; kb < 8; ++kb) {
        bf16x8 af = *((const bf16x8*)(a.agg1b + (size_t)mrow * C1 + kb * 32 + quad * 8));
#pragma unroll
        for (int nt = 0; nt < 3; ++nt) {
            bf16x8 bfr = *((const bf16x8*)(a.W2t + ((nt * 16 + ln) * C1 + kb * 32 + quad * 8)));
            acc[nt] = __builtin_amdgcn_mfma_f32_16x16x32_bf16(af, bfr, acc[nt], 0, 0, 0);
        }
    }
#pragma unroll
    for (int nt = 0; nt < 3; ++nt) {
        int col = nt * 16 + ln;
        if (col < OUT_DIM) {
#pragma unroll
            for (int r = 0; r < 4; ++r) {
                int node = n0 + wv * 16 + quad * 4 + r;
                if (node < a.N) a.h2b[(size_t)node * OUT_DIM + col] = f2bf(acc[nt][r]);
            }
        }
    }
}

__device__ void node2_vb(int vb, const MegaArgs& a, int tid) {
    int w = tid >> 6, lane = tid & 63;
    int n = vb * 4 + w;
    if (n >= a.N) return;
    int start = n << 7;
    int end = start + a.fill[n << 4];
    float adn = a.ad2[n];
    float S = 0.f, acc0 = 0.f, acc1 = 0.f;
    bool act = lane < 20;

    for (int c = start; c < end; c += 64) {
        int cnt = min(64, end - c);
        int idx = c + lane;
        int sreg = (idx < end) ? (int)a.srcs[idx] : 0;
        float ex = (idx < end) ? __expf(leaky(a.as2[sreg] + adn)) : 0.f;
        S += ex;
        int i = 0;
        for (; i + 3 < cnt; i += 4) {
            int su[4]; float al[4]; unsigned rw[4];
#pragma unroll
            for (int k = 0; k < 4; ++k) {
                su[k] = __shfl(sreg, i + k);
                al[k] = __shfl(ex, i + k);
            }
#pragma unroll
            for (int k = 0; k < 4; ++k)
                rw[k] = act ? *(const unsigned*)(a.h2b + (size_t)su[k] * OUT_DIM + lane * 2) : 0u;
#pragma unroll
            for (int k = 0; k < 4; ++k) {
                acc0 += al[k] * __uint_as_float(rw[k] << 16);
                acc1 += al[k] * __uint_as_float(rw[k] & 0xffff0000u);
            }
        }
        for (; i < cnt; ++i) {
            int su0 = __shfl(sreg, i);
            float al0 = __shfl(ex, i);
            unsigned rw0 = act ? *(const unsigned*)(a.h2b + (size_t)su0 * OUT_DIM + lane * 2) : 0u;
            acc0 += al0 * __uint_as_float(rw0 << 16);
            acc1 += al0 * __uint_as_float(rw0 & 0xffff0000u);
        }
    }
#pragma unroll
    for (int o = 32; o > 0; o >>= 1) S += __shfl_xor(S, o);

    float v0 = act ? (acc0 / S + a.bias2[lane * 2]) : -INFINITY;
    float v1 = act ? (acc1 / S + a.bias2[lane * 2 + 1]) : -INFINITY;
    float mx = fmaxf(v0, v1);
#pragma unroll
    for (int o = 16; o > 0; o >>= 1) mx = fmaxf(mx, __shfl_xor(mx, o));
    float e0 = act ? __expf(v0 - mx) : 0.f;
    float e1 = act ? __expf(v1 - mx) : 0.f;
    float esum = e0 + e1;
#pragma unroll
    for (int o = 16; o > 0; o >>= 1) esum += __shfl_xor(esum, o);
    if (act) {
        float l = mx + logf(esum);
        a.out[(size_t)n * OUT_DIM + lane * 2]     = v0 - l;
        a.out[(size_t)n * OUT_DIM + lane * 2 + 1] = v1 - l;
    }
}

// ---------------- the cooperative mega-kernel: 5 phases, 4 grid syncs ----------------
__global__ void __launch_bounds__(256) k_mega(MegaArgs a) {
    cg::grid_group grid = cg::this_grid();
    __shared__ char shbuf[SHBYTES] __attribute__((aligned(16)));
    int t = threadIdx.x;
    int NB = gridDim.x;
    int gtid = blockIdx.x * 256 + t;
    int gsz = NB * 256;

    // ---- P0: prep (fill=0, w2s/w2d, W2t, W1t) ----
    for (int i = gtid; i < a.N; i += gsz) a.fill[i << 4] = 0;
    for (int g = gtid; g < C1; g += gsz) {
        float s = 0.0f, d = 0.0f;
#pragma unroll
        for (int j = 0; j < OUT_DIM; ++j) {
            float w = a.W2[g * OUT_DIM + j];
            s += w * a.a_src2[j];
            d += w * a.a_dst2[j];
        }
        a.w2s[g] = s;
        a.w2d[g] = d;
    }
    for (int g = gtid; g < W2PAD * C1; g += gsz) {
        int j = g >> 8, k = g & 255;
        a.W2t[g] = (j < OUT_DIM) ? f2bf(a.W2[k * OUT_DIM + j]) : 0;
    }
    for (int vb = blockIdx.x; vb < 64; vb += NB)
        prep_w1t_tile(shbuf, vb, a.W1, a.W1t, t);
    grid.sync();

    // ---- P1: layer-1 MFMA GEMM + padded-CSR scatter ----
    for (int vb = blockIdx.x; vb < a.G1 + a.GS; vb += NB) {
        if (vb < a.G1) gemm1_tile(shbuf, vb, a, t);
        else           scatter_chunk(vb - a.G1, a, t);
    }
    grid.sync();

    // ---- P2: node1 ----
    int NV1 = (a.N + 3) / 4;
    for (int vb = blockIdx.x; vb < NV1; vb += NB)
        node1_vb(shbuf, vb, a, t);
    grid.sync();

    // ---- P3: gemm2 ----
    int NV3 = (a.N + 63) / 64;
    for (int vb = blockIdx.x; vb < NV3; vb += NB)
        gemm2m_vb(vb, a, t);
    grid.sync();

    // ---- P4: node2 ----
    for (int vb = blockIdx.x; vb < NV1; vb += NB)
        node2_vb(vb, a, t);
}

extern "C" void kernel_launch(void* const* d_in, const int* in_sizes, int n_in,
                              void* d_out, int out_size, void* d_ws, size_t ws_size,
                              hipStream_t stream) {
    const int N  = in_sizes[0] / IN_DIM;   // 10000
    const int E  = in_sizes[1] / 2;        // 320000
    const int ET = E + N;                  // 330000
    const int Npad = (N + 63) & ~63;

    char* base = (char*)d_ws;
    auto alloc = [&](size_t bytes) {
        char* p = base;
        base += (bytes + 255) & ~(size_t)255;
        return p;
    };
    MegaArgs a;
    a.x        = (const float*)d_in[0];
    a.ei       = (const int*)d_in[1];
    a.W1       = (const float*)d_in[2];
    a.a_src1   = (const float*)d_in[3];
    a.a_dst1   = (const float*)d_in[4];
    a.bias1    = (const float*)d_in[5];
    a.W2       = (const float*)d_in[6];
    a.a_src2   = (const float*)d_in[7];
    a.a_dst2   = (const float*)d_in[8];
    a.bias2    = (const float*)d_in[9];
    a.out      = (float*)d_out;
    a.h1    = (unsigned char*)alloc((size_t)N * C1);            // fp8
    a.W1t   = (unsigned short*)alloc((size_t)C1 * C1 * 2);
    a.W2t   = (unsigned short*)alloc((size_t)W2PAD * C1 * 2);
    a.agg1b = (unsigned short*)alloc((size_t)Npad * C1 * 2);
    a.h2b   = (unsigned short*)alloc((size_t)N * OUT_DIM * 2);  // bf16
    a.as1   = (float*)alloc((size_t)N * H1 * 4);
    a.ad1   = (float*)alloc((size_t)N * H1 * 4);
    a.as2   = (float*)alloc((size_t)N * 4);
    a.ad2   = (float*)alloc((size_t)N * 4);
    a.w2s   = (float*)alloc((size_t)C1 * 4);
    a.w2d   = (float*)alloc((size_t)C1 * 4);
    a.fill  = (int*)alloc((size_t)N * 16 * 4);                  // 1 counter / 64B line
    a.srcs  = (unsigned short*)alloc((size_t)N * DSTRIDE * 2);  // padded CSR, u16
    a.N = N; a.E = E; a.ET = ET;
    a.G1 = (N + 63) / 64;
    a.GS = (ET + 2047) / 2048;

    // co-resident grid: query occupancy, cap at 1024 blocks (4/CU)
    int maxB = 0;
    (void)hipOccupancyMaxActiveBlocksPerMultiprocessor(&maxB, k_mega, 256, 0);
    if (maxB < 1) maxB = 1;
    int NB = 256 * maxB;
    if (NB > 1024) NB = 1024;

    void* kargs[] = {(void*)&a};
    hipLaunchCooperativeKernel((void*)k_mega, dim3(NB), dim3(256), kargs, 0, stream);
}

// Round 14
// 142.132 us; speedup vs baseline: 2.3589x; 2.3589x over previous
//
#include <hip/hip_runtime.h>
#include <hip/hip_bf16.h>
#include <math.h>

// N=10000, E=320000, in_dim=256, heads=4, hidden=64 (C1=256), out=40
#define IN_DIM 256
#define C1 256
#define H1 4
#define OUT_DIM 40
#define W2PAD 48
#define NEG_SLOPE 0.2f
#define DSTRIDE 128  // padded CSR stride; max degree ~58 << 128
// fill: one counter per node, padded to its own 64B line (fill[n<<4])

typedef __attribute__((ext_vector_type(8))) short bf16x8;
typedef __attribute__((ext_vector_type(4))) float f32x4;
typedef __attribute__((ext_vector_type(2))) float f32x2;

#define XS_LD 264  // LDS row stride (u16): 256 + 8 pad

__device__ __forceinline__ unsigned short f2bf(float f) {
    union { float f; unsigned u; } c; c.f = f;
    unsigned r = c.u + 0x7fffu + ((c.u >> 16) & 1u);
    return (unsigned short)(r >> 16);
}

__device__ __forceinline__ unsigned char f2fp8(float f) {
    return (unsigned char)__builtin_amdgcn_cvt_pk_fp8_f32(f, 0.f, 0, false);
}

__device__ __forceinline__ float sel4(float4 v, int h) {
    float r = v.x;
    r = (h == 1) ? v.y : r;
    r = (h == 2) ? v.z : r;
    r = (h == 3) ? v.w : r;
    return r;
}

__device__ __forceinline__ float leaky(float v) {
    return (v >= 0.0f) ? v : NEG_SLOPE * v;
}

// ---------------- prep: fill=0 (padded), w2s/w2d, W1->W1t bf16, W2->W2t bf16 ----------------
__global__ void k_prep(int* __restrict__ fill, const float* __restrict__ W1,
                       unsigned short* __restrict__ W1t, const float* __restrict__ W2,
                       unsigned short* __restrict__ W2t, const float* __restrict__ a_src2,
                       const float* __restrict__ a_dst2, float* __restrict__ w2s,
                       float* __restrict__ w2d, int N) {
    int t = threadIdx.x;
    int g = blockIdx.x * 256 + t;
    if (g < N) fill[g << 4] = 0;
    if (g < C1) {
        float s = 0.0f, d = 0.0f;
#pragma unroll
        for (int j = 0; j < OUT_DIM; ++j) {
            float w = W2[g * OUT_DIM + j];
            s += w * a_src2[j];
            d += w * a_dst2[j];
        }
        w2s[g] = s;
        w2d[g] = d;
    }
    if (g < W2PAD * C1) {  // W2t[j][k] = W2[k][j], rows 40..47 zero
        int j = g >> 8, k = g & 255;
        W2t[g] = (j < OUT_DIM) ? f2bf(W2[k * OUT_DIM + j]) : 0;
    }
    // W1t: 64 blocks = 8x8 tiles of 32x32, transpose via LDS
    __shared__ float s32[32][33];
    int b = blockIdx.x;
    int r0 = (b >> 3) * 32;   // k
    int c0 = (b & 7) * 32;    // col
    for (int i = t; i < 1024; i += 256) {
        int lr = i >> 5, lc = i & 31;
        s32[lr][lc] = W1[(r0 + lr) * 256 + c0 + lc];
    }
    __syncthreads();
    for (int i = t; i < 1024; i += 256) {
        int oc = i >> 5, ok = i & 31;
        W1t[(c0 + oc) * 256 + r0 + ok] = f2bf(s32[ok][oc]);
    }
}

// ---------------- fused: layer-1 MFMA GEMM (blocks [0,G1)) + padded-CSR scatter (rest) ----------------
__global__ void __launch_bounds__(256) k_fused1(
    const float* __restrict__ x, const unsigned short* __restrict__ W1t,
    const float* __restrict__ a_src, const float* __restrict__ a_dst,
    unsigned char* __restrict__ h1, float* __restrict__ as1, float* __restrict__ ad1,
    const int* __restrict__ ei, int* __restrict__ fill, unsigned short* __restrict__ srcs,
    int N, int E, int ET, int G1) {
    __shared__ unsigned short xs[64 * XS_LD];
    int t = threadIdx.x;

    if (blockIdx.x >= G1) {
        int eb = (blockIdx.x - G1) * 1024 + t;
#pragma unroll
        for (int k = 0; k < 4; ++k) {
            int e = eb + k * 256;
            if (e < ET) {
                int s, d;
                if (e < E) { s = ei[e]; d = ei[E + e]; }
                else       { s = e - E; d = s; }
                int pos = atomicAdd(&fill[d << 4], 1);
                srcs[(d << 7) + pos] = (unsigned short)s;
            }
        }
        return;
    }

    int n0 = blockIdx.x * 64;
    for (int i = t; i < 4096; i += 256) {
        int r = i >> 6, c4 = i & 63;
        int n = n0 + r;
        float4 v = (n < N) ? ((const float4*)x)[(size_t)n * 64 + c4]
                           : make_float4(0.f, 0.f, 0.f, 0.f);
        uint2 pk;
        pk.x = (unsigned)f2bf(v.x) | ((unsigned)f2bf(v.y) << 16);
        pk.y = (unsigned)f2bf(v.z) | ((unsigned)f2bf(v.w) << 16);
        *((uint2*)&xs[r * XS_LD + c4 * 4]) = pk;
    }
    __syncthreads();

    int wv = t >> 6, lane = t & 63;
    int quad = lane >> 4, ln = lane & 15;

    f32x4 acc[4][4];
#pragma unroll
    for (int mt = 0; mt < 4; ++mt)
#pragma unroll
        for (int nt = 0; nt < 4; ++nt) acc[mt][nt] = (f32x4){0.f, 0.f, 0.f, 0.f};

#pragma unroll
    for (int kb = 0; kb < 8; ++kb) {
        bf16x8 af[4], bf[4];
#pragma unroll
        for (int mt = 0; mt < 4; ++mt)
            af[mt] = *((bf16x8*)&xs[(mt * 16 + ln) * XS_LD + kb * 32 + quad * 8]);
#pragma unroll
        for (int nt = 0; nt < 4; ++nt)
            bf[nt] = *((const bf16x8*)(W1t + ((wv * 64 + nt * 16 + ln) * 256 + kb * 32 + quad * 8)));
#pragma unroll
        for (int mt = 0; mt < 4; ++mt)
#pragma unroll
            for (int nt = 0; nt < 4; ++nt)
                acc[mt][nt] = __builtin_amdgcn_mfma_f32_16x16x32_bf16(af[mt], bf[nt], acc[mt][nt], 0, 0, 0);
    }

    // attention dots from registers
    float asv[4], adv[4];
#pragma unroll
    for (int nt = 0; nt < 4; ++nt) {
        int col = wv * 64 + nt * 16 + ln;
        asv[nt] = a_src[col];
        adv[nt] = a_dst[col];
    }
#pragma unroll
    for (int mt = 0; mt < 4; ++mt) {
        float ds[4] = {0.f, 0.f, 0.f, 0.f};
        float dd[4] = {0.f, 0.f, 0.f, 0.f};
#pragma unroll
        for (int nt = 0; nt < 4; ++nt) {
#pragma unroll
            for (int r = 0; r < 4; ++r) {
                float v = acc[mt][nt][r];
                ds[r] += v * asv[nt];
                dd[r] += v * adv[nt];
            }
        }
#pragma unroll
        for (int r = 0; r < 4; ++r) {
            float vs = ds[r], vd = dd[r];
#pragma unroll
            for (int o = 1; o < 16; o <<= 1) {
                vs += __shfl_xor(vs, o);
                vd += __shfl_xor(vd, o);
            }
            if (ln == 0) {
                int node = n0 + mt * 16 + quad * 4 + r;
                if (node < N) {
                    as1[node * H1 + wv] = vs;
                    ad1[node * H1 + wv] = vd;
                }
            }
        }
    }

    // h1 store: repack fp8 tile through LDS -> coalesced dwordx4 row stores
    __syncthreads();
    unsigned char* bt = (unsigned char*)xs;  // 64 x 256 byte tile
#pragma unroll
    for (int mt = 0; mt < 4; ++mt)
#pragma unroll
        for (int nt = 0; nt < 4; ++nt)
#pragma unroll
            for (int r = 0; r < 4; ++r)
                bt[(mt * 16 + quad * 4 + r) * 256 + wv * 64 + nt * 16 + ln] = f2fp8(acc[mt][nt][r]);
    __syncthreads();
    const uint4* bt4 = (const uint4*)bt;
    uint4* h14 = (uint4*)(h1 + (size_t)n0 * C1);
    for (int i = t; i < 1024; i += 256) {
        int row = i >> 4;
        if (n0 + row < N) h14[i] = bt4[i];
    }
}

// ---------------- layer 1 node: wave-per-node softmax+aggregate, fused layer-2 GEMM (MFMA) ----------------
// block = 256 (4 waves = 4 nodes). Epilogue: 4 relu'd bf16 rows -> LDS A-buffer ->
// 16x48x256 MFMA tile vs W2t -> h2b direct. No agg1b round trip, no gemm2 kernel.
__global__ void __launch_bounds__(256) k_node1(
    const int* __restrict__ fill, const unsigned short* __restrict__ srcs,
    const float* __restrict__ as1f, const float* __restrict__ ad1f,
    const unsigned char* __restrict__ h1, const float* __restrict__ bias1,
    const float* __restrict__ w2s, const float* __restrict__ w2d,
    const unsigned short* __restrict__ W2t, unsigned short* __restrict__ h2b,
    float* __restrict__ as2, float* __restrict__ ad2, int N) {
    int w = threadIdx.x >> 6, lane = threadIdx.x & 63;
    int n = blockIdx.x * 4 + w;
    bool valid = (n < N);
    __shared__ float4 es[4][64];
    __shared__ unsigned short Abuf[16 * 256];  // 16 rows (4 valid) x 256 bf16
    int start = n << 7;
    int end = start + (valid ? fill[n << 4] : 0);
    const float4* as4 = (const float4*)as1f;
    float4 adn = valid ? ((const float4*)ad1f)[n] : make_float4(0.f, 0.f, 0.f, 0.f);
    int h = lane >> 4;
    const float* esw = (const float*)&es[w][0];

    float4 S4 = make_float4(0.f, 0.f, 0.f, 0.f);
    float ac0 = 0.f, ac1 = 0.f, ac2 = 0.f, ac3 = 0.f;

    for (int c = start; c < end; c += 64) {
        int cnt = min(64, end - c);
        int idx = c + lane;
        int sreg = (idx < end) ? (int)srcs[idx] : 0;
        float4 ex = make_float4(0.f, 0.f, 0.f, 0.f);
        if (idx < end) {
            float4 a = as4[sreg];
            ex.x = __expf(leaky(a.x + adn.x));
            ex.y = __expf(leaky(a.y + adn.y));
            ex.z = __expf(leaky(a.z + adn.z));
            ex.w = __expf(leaky(a.w + adn.w));
        }
        S4.x += ex.x; S4.y += ex.y; S4.z += ex.z; S4.w += ex.w;
        es[w][lane] = ex;

        int i = 0;
        for (; i + 7 < cnt; i += 8) {
            int s[8]; float a[8]; unsigned r[8];
#pragma unroll
            for (int k = 0; k < 8; ++k) {
                s[k] = __shfl(sreg, i + k);
                a[k] = esw[(i + k) * 4 + h];
            }
#pragma unroll
            for (int k = 0; k < 8; ++k)
                r[k] = ((const unsigned*)(h1 + (size_t)s[k] * C1))[lane];
#pragma unroll
            for (int k = 0; k < 8; ++k) {
                f32x2 lo = __builtin_amdgcn_cvt_pk_f32_fp8(r[k], false);
                f32x2 hi = __builtin_amdgcn_cvt_pk_f32_fp8(r[k], true);
                ac0 += a[k] * lo.x;
                ac1 += a[k] * lo.y;
                ac2 += a[k] * hi.x;
                ac3 += a[k] * hi.y;
            }
        }
        for (; i < cnt; ++i) {
            int s0 = __shfl(sreg, i);
            float a0 = esw[i * 4 + h];
            unsigned r0 = ((const unsigned*)(h1 + (size_t)s0 * C1))[lane];
            f32x2 lo = __builtin_amdgcn_cvt_pk_f32_fp8(r0, false);
            f32x2 hi = __builtin_amdgcn_cvt_pk_f32_fp8(r0, true);
            ac0 += a0 * lo.x;
            ac1 += a0 * lo.y;
            ac2 += a0 * hi.x;
            ac3 += a0 * hi.y;
        }
    }

#pragma unroll
    for (int o = 32; o > 0; o >>= 1) {
        S4.x += __shfl_xor(S4.x, o);
        S4.y += __shfl_xor(S4.y, o);
        S4.z += __shfl_xor(S4.z, o);
        S4.w += __shfl_xor(S4.w, o);
    }
    float iS = 1.0f / sel4(S4, h);
    float4 b = ((const float4*)bias1)[lane];
    float v0 = fmaxf(ac0 * iS + b.x, 0.f);
    float v1 = fmaxf(ac1 * iS + b.y, 0.f);
    float v2 = fmaxf(ac2 * iS + b.z, 0.f);
    float v3 = fmaxf(ac3 * iS + b.w, 0.f);
    uint2 pk;
    pk.x = (unsigned)f2bf(v0) | ((unsigned)f2bf(v1) << 16);
    pk.y = (unsigned)f2bf(v2) | ((unsigned)f2bf(v3) << 16);
    ((uint2*)&Abuf[w * 256])[lane] = pk;   // row w of the A-tile

    float4 ws = ((const float4*)w2s)[lane];
    float4 wd = ((const float4*)w2d)[lane];
    float ps = v0 * ws.x + v1 * ws.y + v2 * ws.z + v3 * ws.w;
    float pd = v0 * wd.x + v1 * wd.y + v2 * wd.z + v3 * wd.w;
#pragma unroll
    for (int o = 32; o > 0; o >>= 1) {
        ps += __shfl_xor(ps, o);
        pd += __shfl_xor(pd, o);
    }
    if (lane == 0 && valid) { as2[n] = ps; ad2[n] = pd; }

    // fused layer-2 GEMM: 16(rows, 4 valid) x 48 x 256 MFMA vs W2t; waves 0-2 take n-tiles
    __syncthreads();
    if (w < 3) {
        int quad = lane >> 4, ln = lane & 15;
        f32x4 acc = (f32x4){0.f, 0.f, 0.f, 0.f};
        const unsigned short* bbase = W2t + (w * 16 + ln) * 256;
#pragma unroll
        for (int kb = 0; kb < 8; ++kb) {
            bf16x8 af = *((bf16x8*)&Abuf[ln * 256 + kb * 32 + quad * 8]);
            bf16x8 bfr = *((const bf16x8*)(bbase + kb * 32 + quad * 8));
            acc = __builtin_amdgcn_mfma_f32_16x16x32_bf16(af, bfr, acc, 0, 0, 0);
        }
        int col = w * 16 + ln;
        if (col < OUT_DIM && quad == 0) {  // valid rows m=0..3 live in quad 0
#pragma unroll
            for (int r = 0; r < 4; ++r) {
                int node = blockIdx.x * 4 + r;
                if (node < N) h2b[(size_t)node * OUT_DIM + col] = f2bf(acc[r]);
            }
        }
    }
}

// ---------------- layer 2 node: wave-per-node single-pass + bf16 gather + log_softmax ----------------
__global__ void __launch_bounds__(256) k_node2(
    const int* __restrict__ fill, const unsigned short* __restrict__ srcs,
    const float* __restrict__ as2, const float* __restrict__ ad2,
    const unsigned short* __restrict__ h2b, const float* __restrict__ bias2,
    float* __restrict__ out, int N) {
    int w = threadIdx.x >> 6, lane = threadIdx.x & 63;
    int n = blockIdx.x * 4 + w;
    if (n >= N) return;
    int start = n << 7;
    int end = start + fill[n << 4];
    float adn = ad2[n];
    float S = 0.f, acc0 = 0.f, acc1 = 0.f;
    bool act = lane < 20;

    for (int c = start; c < end; c += 64) {
        int cnt = min(64, end - c);
        int idx = c + lane;
        int sreg = (idx < end) ? (int)srcs[idx] : 0;
        float ex = (idx < end) ? __expf(leaky(as2[sreg] + adn)) : 0.f;
        S += ex;
        int i = 0;
        for (; i + 3 < cnt; i += 4) {
            int su[4]; float al[4]; unsigned rw[4];
#pragma unroll
            for (int k = 0; k < 4; ++k) {
                su[k] = __shfl(sreg, i + k);
                al[k] = __shfl(ex, i + k);
            }
#pragma unroll
            for (int k = 0; k < 4; ++k)
                rw[k] = act ? *(const unsigned*)(h2b + (size_t)su[k] * OUT_DIM + lane * 2) : 0u;
#pragma unroll
            for (int k = 0; k < 4; ++k) {
                acc0 += al[k] * __uint_as_float(rw[k] << 16);
                acc1 += al[k] * __uint_as_float(rw[k] & 0xffff0000u);
            }
        }
        for (; i < cnt; ++i) {
            int su0 = __shfl(sreg, i);
            float al0 = __shfl(ex, i);
            unsigned rw0 = act ? *(const unsigned*)(h2b + (size_t)su0 * OUT_DIM + lane * 2) : 0u;
            acc0 += al0 * __uint_as_float(rw0 << 16);
            acc1 += al0 * __uint_as_float(rw0 & 0xffff0000u);
        }
    }
#pragma unroll
    for (int o = 32; o > 0; o >>= 1) S += __shfl_xor(S, o);

    float v0 = act ? (acc0 / S + bias2[lane * 2]) : -INFINITY;
    float v1 = act ? (acc1 / S + bias2[lane * 2 + 1]) : -INFINITY;
    float mx = fmaxf(v0, v1);
#pragma unroll
    for (int o = 16; o > 0; o >>= 1) mx = fmaxf(mx, __shfl_xor(mx, o));
    float e0 = act ? __expf(v0 - mx) : 0.f;
    float e1 = act ? __expf(v1 - mx) : 0.f;
    float esum = e0 + e1;
#pragma unroll
    for (int o = 16; o > 0; o >>= 1) esum += __shfl_xor(esum, o);
    if (act) {
        float l = mx + logf(esum);
        out[(size_t)n * OUT_DIM + lane * 2]     = v0 - l;
        out[(size_t)n * OUT_DIM + lane * 2 + 1] = v1 - l;
    }
}

extern "C" void kernel_launch(void* const* d_in, const int* in_sizes, int n_in,
                              void* d_out, int out_size, void* d_ws, size_t ws_size,
                              hipStream_t stream) {
    const float* x        = (const float*)d_in[0];
    const int*   ei       = (const int*)d_in[1];
    const float* W1       = (const float*)d_in[2];
    const float* att_src1 = (const float*)d_in[3];
    const float* att_dst1 = (const float*)d_in[4];
    const float* bias1    = (const float*)d_in[5];
    const float* W2       = (const float*)d_in[6];
    const float* att_src2 = (const float*)d_in[7];
    const float* att_dst2 = (const float*)d_in[8];
    const float* bias2    = (const float*)d_in[9];
    float* out = (float*)d_out;

    const int N  = in_sizes[0] / IN_DIM;   // 10000
    const int E  = in_sizes[1] / 2;        // 320000
    const int ET = E + N;                  // 330000

    char* base = (char*)d_ws;
    auto alloc = [&](size_t bytes) {
        char* p = base;
        base += (bytes + 255) & ~(size_t)255;
        return p;
    };
    unsigned char*  h1    = (unsigned char*)alloc((size_t)N * C1);          // fp8
    unsigned short* W1t   = (unsigned short*)alloc((size_t)C1 * C1 * 2);
    unsigned short* W2t   = (unsigned short*)alloc((size_t)W2PAD * C1 * 2);
    unsigned short* h2b   = (unsigned short*)alloc((size_t)N * OUT_DIM * 2);  // bf16
    float* as1   = (float*)alloc((size_t)N * H1 * 4);
    float* ad1   = (float*)alloc((size_t)N * H1 * 4);
    float* as2   = (float*)alloc((size_t)N * 4);
    float* ad2   = (float*)alloc((size_t)N * 4);
    float* w2s   = (float*)alloc((size_t)C1 * 4);
    float* w2d   = (float*)alloc((size_t)C1 * 4);
    int* fill    = (int*)alloc((size_t)N * 16 * 4);  // 1 counter / 64B line
    unsigned short* srcs = (unsigned short*)alloc((size_t)N * DSTRIDE * 2);  // padded CSR, u16

    const int G1 = (N + 63) / 64;             // gemm blocks
    const int GS = (ET + 1023) / 1024;        // scatter blocks (4 edges/thread)

    k_prep<<<64, 256, 0, stream>>>(fill, W1, W1t, W2, W2t, att_src2, att_dst2, w2s, w2d, N);
    k_fused1<<<G1 + GS, 256, 0, stream>>>(x, W1t, att_src1, att_dst1, h1, as1, ad1,
                                          ei, fill, srcs, N, E, ET, G1);
    k_node1<<<(N + 3) / 4, 256, 0, stream>>>(fill, srcs, as1, ad1, h1, bias1, w2s, w2d,
                                             W2t, h2b, as2, ad2, N);
    k_node2<<<(N + 3) / 4, 256, 0, stream>>>(fill, srcs, as2, ad2, h2b, bias2, out, N);
}